// Round 6
// baseline (9307.545 us; speedup 1.0000x reference)
//
#include <hip/hip_runtime.h>
#include <math.h>

// Problem constants
#define BB 2
#define TT 2048
#define CC 768
#define HH 12
#define NN 64
#define GG 2
#define CG 384   // C/G
#define FF 3145728L   // B*C*T
#define S1 1572864L   // B*384*T

// ---------------------------------------------------------------------------
// Generic fp32 tiled GEMM: C(Cout x T) = A(Cout x K) * B(K x T), 64x64 tile,
// 256 threads, 4x4 micro-tile. Template flags:
//   ATRANS: A stored (K x Cout) row-major (ldA = row stride over k)
//   BTRANS: B stored (T x K) row-major (ldB = row stride over t)
//   TOUT:   output stored (T x Cout) row-major (ldC = row stride over t)
//   MODE:   0 none, 1 tanh, 2 mix (out = aux2[m,n]*(aux[m]+acc)),
//           3 ww (decay chain), 4 sigmoid(aux[m]+acc)
// z decomposition: zo = blockIdx.z / zInner, zi = blockIdx.z % zInner
// ---------------------------------------------------------------------------
template<int ATRANS, int BTRANS, int TOUT, int MODE>
__global__ __launch_bounds__(256) void gemm_kernel(
    const float* __restrict__ A, const float* __restrict__ Bm, float* __restrict__ Cm,
    const float* __restrict__ aux, const float* __restrict__ aux2,
    int K, int ldA, int ldB, int ldC, int zInner,
    long sA_o, long sA_i, long sB_o, long sB_i, long sC_o, long sC_i,
    long sAux_i, long sAux2_o)
{
    const int zo = blockIdx.z / zInner;
    const int zi = blockIdx.z % zInner;
    A  += (size_t)zo * sA_o + (size_t)zi * sA_i;
    Bm += (size_t)zo * sB_o + (size_t)zi * sB_i;
    Cm += (size_t)zo * sC_o + (size_t)zi * sC_i;
    if (MODE == 2) { aux += (size_t)zi * sAux_i; aux2 += (size_t)zo * sAux2_o; }

    const int m0t = blockIdx.y * 64;
    const int n0t = blockIdx.x * 64;
    const int tid = threadIdx.x;

    __shared__ float As[16][64];
    __shared__ float Bs[16][64];

    int mi, ni;
    if (TOUT) { mi = (tid & 15) * 4; ni = (tid >> 4) * 4; }
    else      { ni = (tid & 15) * 4; mi = (tid >> 4) * 4; }

    float acc[4][4];
#pragma unroll
    for (int i = 0; i < 4; ++i)
#pragma unroll
        for (int j = 0; j < 4; ++j) acc[i][j] = 0.f;

    for (int k0 = 0; k0 < K; k0 += 16) {
        if (!ATRANS) {
            const int row = tid >> 2;
            const int kc  = (tid & 3) * 4;
            float4 av = *(const float4*)&A[(size_t)(m0t + row) * ldA + k0 + kc];
            As[kc + 0][row] = av.x; As[kc + 1][row] = av.y;
            As[kc + 2][row] = av.z; As[kc + 3][row] = av.w;
        } else {
            const int krow = tid >> 4;
            const int mc   = (tid & 15) * 4;
            *(float4*)&As[krow][mc] = *(const float4*)&A[(size_t)(k0 + krow) * ldA + m0t + mc];
        }
        if (!BTRANS) {
            const int krow = tid >> 4;
            const int tc   = (tid & 15) * 4;
            *(float4*)&Bs[krow][tc] = *(const float4*)&Bm[(size_t)(k0 + krow) * ldB + n0t + tc];
        } else {
            const int trow = tid >> 2;
            const int kc   = (tid & 3) * 4;
            float4 bv = *(const float4*)&Bm[(size_t)(n0t + trow) * ldB + k0 + kc];
            Bs[kc + 0][trow] = bv.x; Bs[kc + 1][trow] = bv.y;
            Bs[kc + 2][trow] = bv.z; Bs[kc + 3][trow] = bv.w;
        }
        __syncthreads();
#pragma unroll
        for (int kk = 0; kk < 16; ++kk) {
            float4 a4 = *(const float4*)&As[kk][mi];
            float4 b4 = *(const float4*)&Bs[kk][ni];
            float am[4] = {a4.x, a4.y, a4.z, a4.w};
            float bn[4] = {b4.x, b4.y, b4.z, b4.w};
#pragma unroll
            for (int i = 0; i < 4; ++i)
#pragma unroll
                for (int j = 0; j < 4; ++j) acc[i][j] = fmaf(am[i], bn[j], acc[i][j]);
        }
        __syncthreads();
    }

    const int mbase = m0t + mi, nbase = n0t + ni;
#pragma unroll
    for (int i = 0; i < 4; ++i) {
        float4 xv;
        if (MODE == 2) xv = *(const float4*)&aux2[(size_t)(mbase + i) * ldC + nbase];
        float xa[4] = {0.f, 0.f, 0.f, 0.f};
        if (MODE == 2) { xa[0] = xv.x; xa[1] = xv.y; xa[2] = xv.z; xa[3] = xv.w; }
#pragma unroll
        for (int j = 0; j < 4; ++j) {
            float v = acc[i][j];
            if (MODE == 1) v = tanhf(v);
            else if (MODE == 2) v = xa[j] * (aux[mbase + i] + v);
            else if (MODE == 3) {
                float u  = aux[mbase + i] + v;
                float sp = fmaxf(-u, 0.f) + log1pf(expf(-fabsf(u)));  // softplus(-u)
                float wl = -sp - 0.5f;
                v = expf(-expf(wl));
            } else if (MODE == 4) {
                float u = aux[mbase + i] + v;
                v = 1.f / (1.f + expf(-u));
            }
            acc[i][j] = v;
        }
    }
    if (!TOUT) {
#pragma unroll
        for (int i = 0; i < 4; ++i) {
            float4 o = {acc[i][0], acc[i][1], acc[i][2], acc[i][3]};
            *(float4*)&Cm[(size_t)(mbase + i) * ldC + nbase] = o;
        }
    } else {
#pragma unroll
        for (int j = 0; j < 4; ++j) {
            float4 o = {acc[0][j], acc[1][j], acc[2][j], acc[3][j]};
            *(float4*)&Cm[(size_t)(nbase + j) * ldC + mbase] = o;
        }
    }
}

// ---------------------------------------------------------------------------
__global__ void pack_aux_kernel(const float* __restrict__ r, const float* __restrict__ w,
                                const float* __restrict__ k, const float* __restrict__ v,
                                const float* __restrict__ a, const float* __restrict__ g,
                                float* __restrict__ paux)
{
    int c = blockIdx.x * blockDim.x + threadIdx.x;
    if (c < CC) {
        paux[0 * CC + c] = 1.f + r[c];
        paux[1 * CC + c] = 1.f + w[c];
        paux[2 * CC + c] = 1.f + k[c];
        paux[3 * CC + c] = 1.f + v[c];
        paux[4 * CC + c] = 1.f + a[c];
        paux[5 * CC + c] = 1.f + g[c];
    }
}

// ---------------------------------------------------------------------------
// E1: per token, kk = k + kvec; per-head L2-normalize; aa=-kkn (over kvec),
// b2=kkn*a (over a). All (B,T,C). One block = one token.
// ---------------------------------------------------------------------------
__global__ __launch_bounds__(256) void e1_kernel(const float* __restrict__ kA,
                                                 float* __restrict__ kvecA,
                                                 float* __restrict__ aA)
{
    const size_t base = (size_t)blockIdx.x * CC;
    const int tid = threadIdx.x;
#pragma unroll
    for (int ch = 0; ch < 3; ++ch) {
        int c = ch * 256 + tid;
        float kk = kA[base + c] + kvecA[base + c];
        float ss = kk * kk;
#pragma unroll
        for (int off = 32; off; off >>= 1) ss += __shfl_xor(ss, off, 64);
        float denom = fmaxf(sqrtf(ss), 1e-12f);
        float kkn = kk / denom;
        float av = aA[base + c];
        kvecA[base + c] = -kkn;       // aa
        aA[base + c]    = kkn * av;   // b2
    }
}

// ---------------------------------------------------------------------------
// WKV-7 recurrence, v6: v5's decomposition (XCD swizzle, 4-way column split,
// direct-global broadcast fragments, 3-deep prefetch) with the in-order
// instruction stream rescheduled so no shfl latency is exposed:
//  - y(t-1)'s reduction shfls are issued BEHIND step t's tmp shfls; the
//    tmp wait is then lgkmcnt(3) (precise), and y's wait lands after the
//    S-update + prefetch-issue (~150 cyc later) -> both DS latencies overlap
//    useful issue.
//  - per-stream base pointers with lane offset folded once; the +16/32/48B
//    go into the load immediates; only the loop induction offset advances.
// No LDS, no barriers (single wave per block).
// ---------------------------------------------------------------------------
struct WFrag {
    float4 w[4], a[4], b[4], k[4], r[4];
    float vv;
};

__global__ __launch_bounds__(64) void wkv_kernel(
    const float* __restrict__ rA, const float* __restrict__ wA,
    const float* __restrict__ kA, const float* __restrict__ vA,
    const float* __restrict__ aaA, const float* __restrict__ b2A,
    float* __restrict__ yA)
{
    const int blk = blockIdx.x;          // rg*24 + bh  (XCD swizzle)
    const int bh = blk % 24, rg = blk / 24;
    const int b = bh / HH, h = bh - b * HH;
    const int lane = threadIdx.x;
    const int jg = lane >> 4, p = lane & 15;
    const int row = rg * 16 + p;
    const size_t base = (size_t)b * TT * CC + h * NN;
    const int fo = jg * 16;

    // per-stream lane-resolved base pointers (address math done once)
    const float* __restrict__ wP = wA  + base + fo;
    const float* __restrict__ aP = aaA + base + fo;
    const float* __restrict__ bP = b2A + base + fo;
    const float* __restrict__ kP = kA  + base + fo;
    const float* __restrict__ rP = rA  + base + fo;
    const float* __restrict__ vP = vA  + base + row;
    float* __restrict__ yP = yA + base + row;

    float S[16];
#pragma unroll
    for (int i = 0; i < 16; ++i) S[i] = 0.f;

    WFrag f[3];

    auto lf = [&](WFrag& g, int t) {
        const size_t o = (size_t)t * CC;
#pragma unroll
        for (int q = 0; q < 4; ++q) {
            g.w[q] = *(const float4*)(wP + o + 4 * q);
            g.a[q] = *(const float4*)(aP + o + 4 * q);
            g.b[q] = *(const float4*)(bP + o + 4 * q);
            g.k[q] = *(const float4*)(kP + o + 4 * q);
            g.r[q] = *(const float4*)(rP + o + 4 * q);
        }
        g.vv = vP[o];
    };

    lf(f[0], 0); lf(f[1], 1); lf(f[2], 2);

    float yprev = 0.f;   // y-partial of step t-1, reduction deferred into step t

    for (int t = 0; t < TT; ++t) {
        WFrag& g = f[t % 3];

        // ---- tmp partial over this lane's 16 columns (on the S chain)
        float t0 = 0.f, t1 = 0.f, t2 = 0.f, t3 = 0.f;
#pragma unroll
        for (int q = 0; q < 4; ++q) {
            float4 a4 = g.a[q];
            t0 = fmaf(S[4*q+0], a4.x, t0);
            t1 = fmaf(S[4*q+1], a4.y, t1);
            t2 = fmaf(S[4*q+2], a4.z, t2);
            t3 = fmaf(S[4*q+3], a4.w, t3);
        }
        float part = (t0 + t1) + (t2 + t3);
        // tmp reduction shfls issued first...
        float s16 = __shfl_xor(part, 16, 64);
        float s32 = __shfl_xor(part, 32, 64);
        float s48 = __shfl_xor(part, 48, 64);
        // ...then y(t-1)'s reduction shfls (waited much later)
        float u16 = __shfl_xor(yprev, 16, 64);
        float u32 = __shfl_xor(yprev, 32, 64);
        float u48 = __shfl_xor(yprev, 48, 64);

        // latency fill: vk (independent of tmp)
        const float vv = g.vv;
        float vk[16];
#pragma unroll
        for (int q = 0; q < 4; ++q) {
            vk[4*q+0] = vv * g.k[q].x;
            vk[4*q+1] = vv * g.k[q].y;
            vk[4*q+2] = vv * g.k[q].z;
            vk[4*q+3] = vv * g.k[q].w;
        }

        // wait for tmp's 3 shfls only (y's stay outstanding)
        float tmp = (part + s16) + (s32 + s48);

        // state update + y partial
        float y0 = 0.f, y1 = 0.f, y2 = 0.f, y3 = 0.f;
#pragma unroll
        for (int q = 0; q < 4; ++q) {
            float4 w4 = g.w[q], b4 = g.b[q], r4 = g.r[q];
            S[4*q+0] = fmaf(S[4*q+0], w4.x, fmaf(tmp, b4.x, vk[4*q+0]));
            y0 = fmaf(S[4*q+0], r4.x, y0);
            S[4*q+1] = fmaf(S[4*q+1], w4.y, fmaf(tmp, b4.y, vk[4*q+1]));
            y1 = fmaf(S[4*q+1], r4.y, y1);
            S[4*q+2] = fmaf(S[4*q+2], w4.z, fmaf(tmp, b4.z, vk[4*q+2]));
            y2 = fmaf(S[4*q+2], r4.z, y2);
            S[4*q+3] = fmaf(S[4*q+3], w4.w, fmaf(tmp, b4.w, vk[4*q+3]));
            y3 = fmaf(S[4*q+3], r4.w, y3);
        }
        float ypart = (y0 + y1) + (y2 + y3);

        // prefetch t+3 into the slot just consumed (VMEM issue fills y's shadow)
        if (t + 3 < TT) lf(g, t + 3);

        // now consume y(t-1)'s shfls (latency long since covered) and store
        if (t > 0 && jg == 0) yP[(size_t)(t - 1) * CC] = (yprev + u16) + (u32 + u48);
        yprev = ypart;
    }
    // final step's y
    {
        float u16 = __shfl_xor(yprev, 16, 64);
        float u32 = __shfl_xor(yprev, 32, 64);
        float u48 = __shfl_xor(yprev, 48, 64);
        if (jg == 0) yP[(size_t)(TT - 1) * CC] = (yprev + u16) + (u32 + u48);
    }
}

// ---------------------------------------------------------------------------
// E2: per token: RMSNorm(y)*lnw + (sum_head r*k*faaaa)*v, times g, write (B,T,C)
// ---------------------------------------------------------------------------
__global__ __launch_bounds__(256) void e2_kernel(
    const float* __restrict__ yA, const float* __restrict__ rA,
    const float* __restrict__ kA, const float* __restrict__ vA,
    const float* __restrict__ gA, const float* __restrict__ faaaa,
    const float* __restrict__ lnw, float* __restrict__ zA)
{
    const size_t base = (size_t)blockIdx.x * CC;
    const int tid = threadIdx.x;
    const int wave = tid >> 6;
    __shared__ float red[4];
    __shared__ float rk[12];

    float yv[3];
    float ss = 0.f;
#pragma unroll
    for (int ch = 0; ch < 3; ++ch) {
        int c = ch * 256 + tid;
        float y = yA[base + c];
        yv[ch] = y;
        ss = fmaf(y, y, ss);
        float p = rA[base + c] * kA[base + c] * faaaa[c];
#pragma unroll
        for (int off = 32; off; off >>= 1) p += __shfl_xor(p, off, 64);
        if ((tid & 63) == 0) rk[ch * 4 + wave] = p;
    }
#pragma unroll
    for (int off = 32; off; off >>= 1) ss += __shfl_xor(ss, off, 64);
    if ((tid & 63) == 0) red[wave] = ss;
    __syncthreads();
    const float total = red[0] + red[1] + red[2] + red[3];
    const float scale = rsqrtf(total / (float)CC + 1e-5f);
#pragma unroll
    for (int ch = 0; ch < 3; ++ch) {
        int c = ch * 256 + tid;
        float out = yv[ch] * scale * lnw[c] + rk[c >> 6] * vA[base + c];
        zA[base + c] = out * gA[base + c];
    }
}

// ---------------------------------------------------------------------------
extern "C" void kernel_launch(void* const* d_in, const int* in_sizes, int n_in,
                              void* d_out, int out_size, void* d_ws, size_t ws_size,
                              hipStream_t stream)
{
    (void)in_sizes; (void)n_in; (void)out_size; (void)ws_size;
    const float* x        = (const float*)d_in[0];
    const float* tmaa_r   = (const float*)d_in[2];
    const float* tmaa_w   = (const float*)d_in[3];
    const float* tmaa_k   = (const float*)d_in[4];
    const float* tmaa_v   = (const float*)d_in[5];
    const float* tmaa_a   = (const float*)d_in[6];
    const float* tmaa_g   = (const float*)d_in[7];
    const float* tdecay   = (const float*)d_in[8];
    const float* tfaaaa   = (const float*)d_in[9];
    const float* taaaaa   = (const float*)d_in[10];
    const float* maa_w1   = (const float*)d_in[11];
    const float* maa_w2   = (const float*)d_in[12];
    const float* decay_w1 = (const float*)d_in[13];
    const float* decay_w2 = (const float*)d_in[14];
    const float* aaa_w1   = (const float*)d_in[15];
    const float* aaa_w2   = (const float*)d_in[16];
    const float* kkk_w1   = (const float*)d_in[17];
    const float* kkk_w2   = (const float*)d_in[18];
    const float* gate_w1  = (const float*)d_in[19];
    const float* gate_w2  = (const float*)d_in[20];
    const float* w_key    = (const float*)d_in[21];
    const float* w_value  = (const float*)d_in[22];
    const float* w_recept = (const float*)d_in[23];
    const float* w_output = (const float*)d_in[24];
    const float* lnw      = (const float*)d_in[25];
    float* out = (float*)d_out;

    float* ws   = (float*)d_ws;
    float* paux = ws;                 // 6*768
    float* tm   = ws + 8192;          // S1
    float* X6   = tm + S1;            // 6*FF
    float* dh   = X6 + 6 * FF;        // B*64*T = 262144
    float* ah   = dh + 262144;
    float* kh   = ah + 262144;
    float* gh   = kh + 262144;        // B*192*T = 786432
    float* gbuf = gh + 786432;        // FF
    float* ybuf = gbuf + FF;          // FF
    float* zbuf = ybuf + FF;          // FF

    float* xr = X6 + 0 * FF; float* xw = X6 + 1 * FF; float* xk = X6 + 2 * FF;
    float* xv = X6 + 3 * FF; float* xa = X6 + 4 * FF; float* xg = X6 + 5 * FF;
    float* wwB = X6 + 0 * FF; float* rB  = X6 + 1 * FF; float* aaB = X6 + 2 * FF;
    float* b2B = X6 + 3 * FF; float* kB  = X6 + 4 * FF; float* vB  = X6 + 5 * FF;

    const long CT = (long)CC * TT;        // 1572864
    const long TC = (long)TT * CC;        // 1572864

    pack_aux_kernel<<<dim3(3), 256, 0, stream>>>(tmaa_r, tmaa_w, tmaa_k, tmaa_v, tmaa_a, tmaa_g, paux);

    // tm = tanh(maa_w1 @ x)   (B,384,T)
    gemm_kernel<0,0,0,1><<<dim3(32, 6, 2), 256, 0, stream>>>(
        maa_w1, x, tm, nullptr, nullptr,
        768, 768, TT, TT, 1,
        0, 0, CT, 0, 384L * TT, 0, 0, 0);

    // X6[n] = x * (paux[n] + maa_w2[n]^T @ tm_n)   z = b*6 + n
    gemm_kernel<1,0,0,2><<<dim3(32, 12, 12), 256, 0, stream>>>(
        maa_w2, tm, X6, paux, x,
        64, 768, TT, TT, 6,
        0, 64L * 768, 384L * TT, 64L * TT, CT, FF, 768, CT);

    // lora hiddens (tanh)
    gemm_kernel<0,0,0,1><<<dim3(32, 1, 2), 256, 0, stream>>>(
        decay_w1, xw, dh, nullptr, nullptr, 768, 768, TT, TT, 1,
        0, 0, CT, 0, 64L * TT, 0, 0, 0);
    gemm_kernel<0,0,0,1><<<dim3(32, 1, 2), 256, 0, stream>>>(
        aaa_w1, xa, ah, nullptr, nullptr, 768, 768, TT, TT, 1,
        0, 0, CT, 0, 64L * TT, 0, 0, 0);
    gemm_kernel<0,0,0,1><<<dim3(32, 1, 2), 256, 0, stream>>>(
        kkk_w1, xk, kh, nullptr, nullptr, 768, 768, TT, TT, 1,
        0, 0, CT, 0, 64L * TT, 0, 0, 0);
    gemm_kernel<0,0,0,1><<<dim3(32, 3, 2), 256, 0, stream>>>(
        gate_w1, xg, gh, nullptr, nullptr, 768, 768, TT, TT, 1,
        0, 0, CT, 0, 192L * TT, 0, 0, 0);

    // grouped convs -> (B,T,C) transposed outputs. z = b*2 + g
    gemm_kernel<0,0,1,0><<<dim3(32, 6, 4), 256, 0, stream>>>(
        w_recept, xr, rB, nullptr, nullptr, 384, 384, TT, CC, 2,
        0, 384L * 384, CT, 384L * TT, TC, 384, 0, 0);
    gemm_kernel<0,0,1,0><<<dim3(32, 6, 4), 256, 0, stream>>>(
        w_key, xk, kB, nullptr, nullptr, 384, 384, TT, CC, 2,
        0, 384L * 384, CT, 384L * TT, TC, 384, 0, 0);
    gemm_kernel<0,0,1,0><<<dim3(32, 6, 4), 256, 0, stream>>>(
        w_value, xv, vB, nullptr, nullptr, 384, 384, TT, CC, 2,
        0, 384L * 384, CT, 384L * TT, TC, 384, 0, 0);

    // lora outs -> (B,T,C)
    gemm_kernel<0,0,1,3><<<dim3(32, 12, 2), 256, 0, stream>>>(
        decay_w2, dh, wwB, tdecay, nullptr, 64, 64, TT, CC, 1,
        0, 0, 64L * TT, 0, TC, 0, 0, 0);
    gemm_kernel<0,0,1,4><<<dim3(32, 12, 2), 256, 0, stream>>>(
        aaa_w2, ah, b2B /* a for now */, taaaaa, nullptr, 64, 64, TT, CC, 1,
        0, 0, 64L * TT, 0, TC, 0, 0, 0);
    gemm_kernel<0,0,1,0><<<dim3(32, 12, 2), 256, 0, stream>>>(
        kkk_w2, kh, aaB /* kvec for now */, nullptr, nullptr, 64, 64, TT, CC, 1,
        0, 0, 64L * TT, 0, TC, 0, 0, 0);
    gemm_kernel<0,0,1,0><<<dim3(32, 12, 2), 256, 0, stream>>>(
        gate_w2, gh, gbuf, nullptr, nullptr, 192, 192, TT, CC, 1,
        0, 0, 192L * TT, 0, TC, 0, 0, 0);

    // E1: build aa (over kvec slot) and b2 (over a slot)
    e1_kernel<<<dim3(BB * TT), 256, 0, stream>>>(kB, aaB, b2B);

    // WKV recurrence v6: cross-step-pipelined reductions
    wkv_kernel<<<dim3(BB * HH * 4), 64, 0, stream>>>(rB, wwB, kB, vB, aaB, b2B, ybuf);

    // E2: rmsnorm + faaaa bonus + gate
    e2_kernel<<<dim3(BB * TT), 256, 0, stream>>>(ybuf, rB, kB, vB, gbuf, tfaaaa, lnw, zbuf);

    // final grouped conv from (B,T,C) z -> (B,C,T) out.  z = b*2 + g
    gemm_kernel<0,1,0,0><<<dim3(32, 6, 4), 256, 0, stream>>>(
        w_output, zbuf, out, nullptr, nullptr, 384, 384, CC, TT, 2,
        0, 384L * 384, TC, 384, CT, 384L * TT, 0, 0);
}

// Round 7
// 1899.107 us; speedup vs baseline: 4.9010x; 4.9010x over previous
//
#include <hip/hip_runtime.h>
#include <math.h>

// Problem constants
#define BB 2
#define TT 2048
#define CC 768
#define HH 12
#define NN 64
#define GG 2
#define CG 384   // C/G
#define FF 3145728L   // B*C*T
#define S1 1572864L   // B*384*T

// ---------------------------------------------------------------------------
// Generic fp32 tiled GEMM: C(Cout x T) = A(Cout x K) * B(K x T), 64x64 tile,
// 256 threads, 4x4 micro-tile. Template flags:
//   ATRANS: A stored (K x Cout) row-major (ldA = row stride over k)
//   BTRANS: B stored (T x K) row-major (ldB = row stride over t)
//   TOUT:   output stored (T x Cout) row-major (ldC = row stride over t)
//   MODE:   0 none, 1 tanh, 2 mix (out = aux2[m,n]*(aux[m]+acc)),
//           3 ww (decay chain), 4 sigmoid(aux[m]+acc)
// z decomposition: zo = blockIdx.z / zInner, zi = blockIdx.z % zInner
// ---------------------------------------------------------------------------
template<int ATRANS, int BTRANS, int TOUT, int MODE>
__global__ __launch_bounds__(256) void gemm_kernel(
    const float* __restrict__ A, const float* __restrict__ Bm, float* __restrict__ Cm,
    const float* __restrict__ aux, const float* __restrict__ aux2,
    int K, int ldA, int ldB, int ldC, int zInner,
    long sA_o, long sA_i, long sB_o, long sB_i, long sC_o, long sC_i,
    long sAux_i, long sAux2_o)
{
    const int zo = blockIdx.z / zInner;
    const int zi = blockIdx.z % zInner;
    A  += (size_t)zo * sA_o + (size_t)zi * sA_i;
    Bm += (size_t)zo * sB_o + (size_t)zi * sB_i;
    Cm += (size_t)zo * sC_o + (size_t)zi * sC_i;
    if (MODE == 2) { aux += (size_t)zi * sAux_i; aux2 += (size_t)zo * sAux2_o; }

    const int m0t = blockIdx.y * 64;
    const int n0t = blockIdx.x * 64;
    const int tid = threadIdx.x;

    __shared__ float As[16][64];
    __shared__ float Bs[16][64];

    int mi, ni;
    if (TOUT) { mi = (tid & 15) * 4; ni = (tid >> 4) * 4; }
    else      { ni = (tid & 15) * 4; mi = (tid >> 4) * 4; }

    float acc[4][4];
#pragma unroll
    for (int i = 0; i < 4; ++i)
#pragma unroll
        for (int j = 0; j < 4; ++j) acc[i][j] = 0.f;

    for (int k0 = 0; k0 < K; k0 += 16) {
        if (!ATRANS) {
            const int row = tid >> 2;
            const int kc  = (tid & 3) * 4;
            float4 av = *(const float4*)&A[(size_t)(m0t + row) * ldA + k0 + kc];
            As[kc + 0][row] = av.x; As[kc + 1][row] = av.y;
            As[kc + 2][row] = av.z; As[kc + 3][row] = av.w;
        } else {
            const int krow = tid >> 4;
            const int mc   = (tid & 15) * 4;
            *(float4*)&As[krow][mc] = *(const float4*)&A[(size_t)(k0 + krow) * ldA + m0t + mc];
        }
        if (!BTRANS) {
            const int krow = tid >> 4;
            const int tc   = (tid & 15) * 4;
            *(float4*)&Bs[krow][tc] = *(const float4*)&Bm[(size_t)(k0 + krow) * ldB + n0t + tc];
        } else {
            const int trow = tid >> 2;
            const int kc   = (tid & 3) * 4;
            float4 bv = *(const float4*)&Bm[(size_t)(n0t + trow) * ldB + k0 + kc];
            Bs[kc + 0][trow] = bv.x; Bs[kc + 1][trow] = bv.y;
            Bs[kc + 2][trow] = bv.z; Bs[kc + 3][trow] = bv.w;
        }
        __syncthreads();
#pragma unroll
        for (int kk = 0; kk < 16; ++kk) {
            float4 a4 = *(const float4*)&As[kk][mi];
            float4 b4 = *(const float4*)&Bs[kk][ni];
            float am[4] = {a4.x, a4.y, a4.z, a4.w};
            float bn[4] = {b4.x, b4.y, b4.z, b4.w};
#pragma unroll
            for (int i = 0; i < 4; ++i)
#pragma unroll
                for (int j = 0; j < 4; ++j) acc[i][j] = fmaf(am[i], bn[j], acc[i][j]);
        }
        __syncthreads();
    }

    const int mbase = m0t + mi, nbase = n0t + ni;
#pragma unroll
    for (int i = 0; i < 4; ++i) {
        float4 xv;
        if (MODE == 2) xv = *(const float4*)&aux2[(size_t)(mbase + i) * ldC + nbase];
        float xa[4] = {0.f, 0.f, 0.f, 0.f};
        if (MODE == 2) { xa[0] = xv.x; xa[1] = xv.y; xa[2] = xv.z; xa[3] = xv.w; }
#pragma unroll
        for (int j = 0; j < 4; ++j) {
            float v = acc[i][j];
            if (MODE == 1) v = tanhf(v);
            else if (MODE == 2) v = xa[j] * (aux[mbase + i] + v);
            else if (MODE == 3) {
                float u  = aux[mbase + i] + v;
                float sp = fmaxf(-u, 0.f) + log1pf(expf(-fabsf(u)));  // softplus(-u)
                float wl = -sp - 0.5f;
                v = expf(-expf(wl));
            } else if (MODE == 4) {
                float u = aux[mbase + i] + v;
                v = 1.f / (1.f + expf(-u));
            }
            acc[i][j] = v;
        }
    }
    if (!TOUT) {
#pragma unroll
        for (int i = 0; i < 4; ++i) {
            float4 o = {acc[i][0], acc[i][1], acc[i][2], acc[i][3]};
            *(float4*)&Cm[(size_t)(mbase + i) * ldC + nbase] = o;
        }
    } else {
#pragma unroll
        for (int j = 0; j < 4; ++j) {
            float4 o = {acc[0][j], acc[1][j], acc[2][j], acc[3][j]};
            *(float4*)&Cm[(size_t)(nbase + j) * ldC + mbase] = o;
        }
    }
}

// ---------------------------------------------------------------------------
__global__ void pack_aux_kernel(const float* __restrict__ r, const float* __restrict__ w,
                                const float* __restrict__ k, const float* __restrict__ v,
                                const float* __restrict__ a, const float* __restrict__ g,
                                float* __restrict__ paux)
{
    int c = blockIdx.x * blockDim.x + threadIdx.x;
    if (c < CC) {
        paux[0 * CC + c] = 1.f + r[c];
        paux[1 * CC + c] = 1.f + w[c];
        paux[2 * CC + c] = 1.f + k[c];
        paux[3 * CC + c] = 1.f + v[c];
        paux[4 * CC + c] = 1.f + a[c];
        paux[5 * CC + c] = 1.f + g[c];
    }
}

// ---------------------------------------------------------------------------
// E1: per token, kk = k + kvec; per-head L2-normalize; aa=-kkn (over kvec),
// b2=kkn*a (over a). All (B,T,C). One block = one token.
// ---------------------------------------------------------------------------
__global__ __launch_bounds__(256) void e1_kernel(const float* __restrict__ kA,
                                                 float* __restrict__ kvecA,
                                                 float* __restrict__ aA)
{
    const size_t base = (size_t)blockIdx.x * CC;
    const int tid = threadIdx.x;
#pragma unroll
    for (int ch = 0; ch < 3; ++ch) {
        int c = ch * 256 + tid;
        float kk = kA[base + c] + kvecA[base + c];
        float ss = kk * kk;
#pragma unroll
        for (int off = 32; off; off >>= 1) ss += __shfl_xor(ss, off, 64);
        float denom = fmaxf(sqrtf(ss), 1e-12f);
        float kkn = kk / denom;
        float av = aA[base + c];
        kvecA[base + c] = -kkn;       // aa
        aA[base + c]    = kkn * av;   // b2
    }
}

// ---------------------------------------------------------------------------
// WKV-7 recurrence, v7 = v5's register-resident structure (NAMED f0/f1/f2,
// unrolled-by-3 loop — v6's f[t%3] runtime indexing spilled all fragments to
// scratch: VGPR 148->72, +6MB scratch writes, 12x slower) + v6's two ideas:
//  (a) y(t-1) reduction deferred into step t: its shfls issue behind tmp's,
//      its wait lands after the S-update + prefetch issue;
//  (b) per-stream lane-folded base pointers, offsets in load immediates.
// No LDS, no barriers (single wave per block).
// ---------------------------------------------------------------------------
struct WFrag {
    float4 w[4], a[4], b[4], k[4], r[4];
    float vv;
};

__global__ __launch_bounds__(64) void wkv_kernel(
    const float* __restrict__ rA, const float* __restrict__ wA,
    const float* __restrict__ kA, const float* __restrict__ vA,
    const float* __restrict__ aaA, const float* __restrict__ b2A,
    float* __restrict__ yA)
{
    const int blk = blockIdx.x;          // rg*24 + bh  (XCD swizzle)
    const int bh = blk % 24, rg = blk / 24;
    const int b = bh / HH, h = bh - b * HH;
    const int lane = threadIdx.x;
    const int jg = lane >> 4, p = lane & 15;
    const int row = rg * 16 + p;
    const size_t base = (size_t)b * TT * CC + h * NN;
    const int fo = jg * 16;

    // per-stream lane-resolved base pointers (address math done once)
    const float* __restrict__ wP = wA  + base + fo;
    const float* __restrict__ aP = aaA + base + fo;
    const float* __restrict__ bP = b2A + base + fo;
    const float* __restrict__ kP = kA  + base + fo;
    const float* __restrict__ rP = rA  + base + fo;
    const float* __restrict__ vP = vA  + base + row;
    float* __restrict__ yP = yA + base + row;

    float S[16];
#pragma unroll
    for (int i = 0; i < 16; ++i) S[i] = 0.f;

    WFrag f0, f1, f2;

    auto lf = [&](WFrag& g, int t) {
        const size_t o = (size_t)t * CC;
#pragma unroll
        for (int q = 0; q < 4; ++q) {
            g.w[q] = *(const float4*)(wP + o + 4 * q);
            g.a[q] = *(const float4*)(aP + o + 4 * q);
            g.b[q] = *(const float4*)(bP + o + 4 * q);
            g.k[q] = *(const float4*)(kP + o + 4 * q);
            g.r[q] = *(const float4*)(rP + o + 4 * q);
        }
        g.vv = vP[o];
    };

    float yprev = 0.f;   // y-partial of step t-1; reduced/stored during step t

    auto stepf = [&](WFrag& g, int t, int tpre) {
        // ---- tmp partial over this lane's 16 columns (on the S chain)
        float t0 = 0.f, t1 = 0.f, t2 = 0.f, t3 = 0.f;
#pragma unroll
        for (int q = 0; q < 4; ++q) {
            float4 a4 = g.a[q];
            t0 = fmaf(S[4*q+0], a4.x, t0);
            t1 = fmaf(S[4*q+1], a4.y, t1);
            t2 = fmaf(S[4*q+2], a4.z, t2);
            t3 = fmaf(S[4*q+3], a4.w, t3);
        }
        float part = (t0 + t1) + (t2 + t3);
        // tmp reduction shfls issued first...
        float s16 = __shfl_xor(part, 16, 64);
        float s32 = __shfl_xor(part, 32, 64);
        float s48 = __shfl_xor(part, 48, 64);
        // ...then y(t-1)'s reduction shfls (consumed much later)
        float u16 = __shfl_xor(yprev, 16, 64);
        float u32 = __shfl_xor(yprev, 32, 64);
        float u48 = __shfl_xor(yprev, 48, 64);

        // latency fill: vk (independent of tmp)
        const float vv = g.vv;
        float vk[16];
#pragma unroll
        for (int q = 0; q < 4; ++q) {
            vk[4*q+0] = vv * g.k[q].x;
            vk[4*q+1] = vv * g.k[q].y;
            vk[4*q+2] = vv * g.k[q].z;
            vk[4*q+3] = vv * g.k[q].w;
        }

        float tmp = (part + s16) + (s32 + s48);

        // state update + y partial
        float y0 = 0.f, y1 = 0.f, y2 = 0.f, y3 = 0.f;
#pragma unroll
        for (int q = 0; q < 4; ++q) {
            float4 w4 = g.w[q], b4 = g.b[q], r4 = g.r[q];
            S[4*q+0] = fmaf(S[4*q+0], w4.x, fmaf(tmp, b4.x, vk[4*q+0]));
            y0 = fmaf(S[4*q+0], r4.x, y0);
            S[4*q+1] = fmaf(S[4*q+1], w4.y, fmaf(tmp, b4.y, vk[4*q+1]));
            y1 = fmaf(S[4*q+1], r4.y, y1);
            S[4*q+2] = fmaf(S[4*q+2], w4.z, fmaf(tmp, b4.z, vk[4*q+2]));
            y2 = fmaf(S[4*q+2], r4.z, y2);
            S[4*q+3] = fmaf(S[4*q+3], w4.w, fmaf(tmp, b4.w, vk[4*q+3]));
            y3 = fmaf(S[4*q+3], r4.w, y3);
        }
        float ypart = (y0 + y1) + (y2 + y3);

        // prefetch tpre into the slot just consumed (VMEM fills y's shadow)
        if (tpre < TT) lf(g, tpre);

        // consume y(t-1)'s shfls (latency long covered) and store
        if (t > 0 && jg == 0) yP[(size_t)(t - 1) * CC] = (yprev + u16) + (u32 + u48);
        yprev = ypart;
    };

    lf(f0, 0); lf(f1, 1); lf(f2, 2);

    int t = 0;
    for (; t + 2 < TT; t += 3) {
        stepf(f0, t,     t + 3);
        stepf(f1, t + 1, t + 4);
        stepf(f2, t + 2, t + 5);
    }
    // tail (TT = 3*682 + 2): two remaining steps, fragments already loaded
    if (t < TT)     stepf(f0, t,     TT);
    if (t + 1 < TT) stepf(f1, t + 1, TT);

    // final step's y
    {
        float u16 = __shfl_xor(yprev, 16, 64);
        float u32 = __shfl_xor(yprev, 32, 64);
        float u48 = __shfl_xor(yprev, 48, 64);
        if (jg == 0) yP[(size_t)(TT - 1) * CC] = (yprev + u16) + (u32 + u48);
    }
}

// ---------------------------------------------------------------------------
// E2: per token: RMSNorm(y)*lnw + (sum_head r*k*faaaa)*v, times g, write (B,T,C)
// ---------------------------------------------------------------------------
__global__ __launch_bounds__(256) void e2_kernel(
    const float* __restrict__ yA, const float* __restrict__ rA,
    const float* __restrict__ kA, const float* __restrict__ vA,
    const float* __restrict__ gA, const float* __restrict__ faaaa,
    const float* __restrict__ lnw, float* __restrict__ zA)
{
    const size_t base = (size_t)blockIdx.x * CC;
    const int tid = threadIdx.x;
    const int wave = tid >> 6;
    __shared__ float red[4];
    __shared__ float rk[12];

    float yv[3];
    float ss = 0.f;
#pragma unroll
    for (int ch = 0; ch < 3; ++ch) {
        int c = ch * 256 + tid;
        float y = yA[base + c];
        yv[ch] = y;
        ss = fmaf(y, y, ss);
        float p = rA[base + c] * kA[base + c] * faaaa[c];
#pragma unroll
        for (int off = 32; off; off >>= 1) p += __shfl_xor(p, off, 64);
        if ((tid & 63) == 0) rk[ch * 4 + wave] = p;
    }
#pragma unroll
    for (int off = 32; off; off >>= 1) ss += __shfl_xor(ss, off, 64);
    if ((tid & 63) == 0) red[wave] = ss;
    __syncthreads();
    const float total = red[0] + red[1] + red[2] + red[3];
    const float scale = rsqrtf(total / (float)CC + 1e-5f);
#pragma unroll
    for (int ch = 0; ch < 3; ++ch) {
        int c = ch * 256 + tid;
        float out = yv[ch] * scale * lnw[c] + rk[c >> 6] * vA[base + c];
        zA[base + c] = out * gA[base + c];
    }
}

// ---------------------------------------------------------------------------
extern "C" void kernel_launch(void* const* d_in, const int* in_sizes, int n_in,
                              void* d_out, int out_size, void* d_ws, size_t ws_size,
                              hipStream_t stream)
{
    (void)in_sizes; (void)n_in; (void)out_size; (void)ws_size;
    const float* x        = (const float*)d_in[0];
    const float* tmaa_r   = (const float*)d_in[2];
    const float* tmaa_w   = (const float*)d_in[3];
    const float* tmaa_k   = (const float*)d_in[4];
    const float* tmaa_v   = (const float*)d_in[5];
    const float* tmaa_a   = (const float*)d_in[6];
    const float* tmaa_g   = (const float*)d_in[7];
    const float* tdecay   = (const float*)d_in[8];
    const float* tfaaaa   = (const float*)d_in[9];
    const float* taaaaa   = (const float*)d_in[10];
    const float* maa_w1   = (const float*)d_in[11];
    const float* maa_w2   = (const float*)d_in[12];
    const float* decay_w1 = (const float*)d_in[13];
    const float* decay_w2 = (const float*)d_in[14];
    const float* aaa_w1   = (const float*)d_in[15];
    const float* aaa_w2   = (const float*)d_in[16];
    const float* kkk_w1   = (const float*)d_in[17];
    const float* kkk_w2   = (const float*)d_in[18];
    const float* gate_w1  = (const float*)d_in[19];
    const float* gate_w2  = (const float*)d_in[20];
    const float* w_key    = (const float*)d_in[21];
    const float* w_value  = (const float*)d_in[22];
    const float* w_recept = (const float*)d_in[23];
    const float* w_output = (const float*)d_in[24];
    const float* lnw      = (const float*)d_in[25];
    float* out = (float*)d_out;

    float* ws   = (float*)d_ws;
    float* paux = ws;                 // 6*768
    float* tm   = ws + 8192;          // S1
    float* X6   = tm + S1;            // 6*FF
    float* dh   = X6 + 6 * FF;        // B*64*T = 262144
    float* ah   = dh + 262144;
    float* kh   = ah + 262144;
    float* gh   = kh + 262144;        // B*192*T = 786432
    float* gbuf = gh + 786432;        // FF
    float* ybuf = gbuf + FF;          // FF
    float* zbuf = ybuf + FF;          // FF

    float* xr = X6 + 0 * FF; float* xw = X6 + 1 * FF; float* xk = X6 + 2 * FF;
    float* xv = X6 + 3 * FF; float* xa = X6 + 4 * FF; float* xg = X6 + 5 * FF;
    float* wwB = X6 + 0 * FF; float* rB  = X6 + 1 * FF; float* aaB = X6 + 2 * FF;
    float* b2B = X6 + 3 * FF; float* kB  = X6 + 4 * FF; float* vB  = X6 + 5 * FF;

    const long CT = (long)CC * TT;        // 1572864
    const long TC = (long)TT * CC;        // 1572864

    pack_aux_kernel<<<dim3(3), 256, 0, stream>>>(tmaa_r, tmaa_w, tmaa_k, tmaa_v, tmaa_a, tmaa_g, paux);

    // tm = tanh(maa_w1 @ x)   (B,384,T)
    gemm_kernel<0,0,0,1><<<dim3(32, 6, 2), 256, 0, stream>>>(
        maa_w1, x, tm, nullptr, nullptr,
        768, 768, TT, TT, 1,
        0, 0, CT, 0, 384L * TT, 0, 0, 0);

    // X6[n] = x * (paux[n] + maa_w2[n]^T @ tm_n)   z = b*6 + n
    gemm_kernel<1,0,0,2><<<dim3(32, 12, 12), 256, 0, stream>>>(
        maa_w2, tm, X6, paux, x,
        64, 768, TT, TT, 6,
        0, 64L * 768, 384L * TT, 64L * TT, CT, FF, 768, CT);

    // lora hiddens (tanh)
    gemm_kernel<0,0,0,1><<<dim3(32, 1, 2), 256, 0, stream>>>(
        decay_w1, xw, dh, nullptr, nullptr, 768, 768, TT, TT, 1,
        0, 0, CT, 0, 64L * TT, 0, 0, 0);
    gemm_kernel<0,0,0,1><<<dim3(32, 1, 2), 256, 0, stream>>>(
        aaa_w1, xa, ah, nullptr, nullptr, 768, 768, TT, TT, 1,
        0, 0, CT, 0, 64L * TT, 0, 0, 0);
    gemm_kernel<0,0,0,1><<<dim3(32, 1, 2), 256, 0, stream>>>(
        kkk_w1, xk, kh, nullptr, nullptr, 768, 768, TT, TT, 1,
        0, 0, CT, 0, 64L * TT, 0, 0, 0);
    gemm_kernel<0,0,0,1><<<dim3(32, 3, 2), 256, 0, stream>>>(
        gate_w1, xg, gh, nullptr, nullptr, 768, 768, TT, TT, 1,
        0, 0, CT, 0, 192L * TT, 0, 0, 0);

    // grouped convs -> (B,T,C) transposed outputs. z = b*2 + g
    gemm_kernel<0,0,1,0><<<dim3(32, 6, 4), 256, 0, stream>>>(
        w_recept, xr, rB, nullptr, nullptr, 384, 384, TT, CC, 2,
        0, 384L * 384, CT, 384L * TT, TC, 384, 0, 0);
    gemm_kernel<0,0,1,0><<<dim3(32, 6, 4), 256, 0, stream>>>(
        w_key, xk, kB, nullptr, nullptr, 384, 384, TT, CC, 2,
        0, 384L * 384, CT, 384L * TT, TC, 384, 0, 0);
    gemm_kernel<0,0,1,0><<<dim3(32, 6, 4), 256, 0, stream>>>(
        w_value, xv, vB, nullptr, nullptr, 384, 384, TT, CC, 2,
        0, 384L * 384, CT, 384L * TT, TC, 384, 0, 0);

    // lora outs -> (B,T,C)
    gemm_kernel<0,0,1,3><<<dim3(32, 12, 2), 256, 0, stream>>>(
        decay_w2, dh, wwB, tdecay, nullptr, 64, 64, TT, CC, 1,
        0, 0, 64L * TT, 0, TC, 0, 0, 0);
    gemm_kernel<0,0,1,4><<<dim3(32, 12, 2), 256, 0, stream>>>(
        aaa_w2, ah, b2B /* a for now */, taaaaa, nullptr, 64, 64, TT, CC, 1,
        0, 0, 64L * TT, 0, TC, 0, 0, 0);
    gemm_kernel<0,0,1,0><<<dim3(32, 12, 2), 256, 0, stream>>>(
        kkk_w2, kh, aaB /* kvec for now */, nullptr, nullptr, 64, 64, TT, CC, 1,
        0, 0, 64L * TT, 0, TC, 0, 0, 0);
    gemm_kernel<0,0,1,0><<<dim3(32, 12, 2), 256, 0, stream>>>(
        gate_w2, gh, gbuf, nullptr, nullptr, 192, 192, TT, CC, 1,
        0, 0, 192L * TT, 0, TC, 0, 0, 0);

    // E1: build aa (over kvec slot) and b2 (over a slot)
    e1_kernel<<<dim3(BB * TT), 256, 0, stream>>>(kB, aaB, b2B);

    // WKV recurrence v7: named-fragment (register-resident) deferred-y pipeline
    wkv_kernel<<<dim3(BB * HH * 4), 64, 0, stream>>>(rB, wwB, kB, vB, aaB, b2B, ybuf);

    // E2: rmsnorm + faaaa bonus + gate
    e2_kernel<<<dim3(BB * TT), 256, 0, stream>>>(ybuf, rB, kB, vB, gbuf, tfaaaa, lnw, zbuf);

    // final grouped conv from (B,T,C) z -> (B,C,T) out.  z = b*2 + g
    gemm_kernel<0,1,0,0><<<dim3(32, 6, 4), 256, 0, stream>>>(
        w_output, zbuf, out, nullptr, nullptr, 384, 384, CC, TT, 2,
        0, 384L * 384, TC, 384, CT, 384L * TT, 0, 0);
}

// Round 8
// 1265.311 us; speedup vs baseline: 7.3559x; 1.5009x over previous
//
#include <hip/hip_runtime.h>
#include <math.h>

// Problem constants
#define BB 2
#define TT 2048
#define CC 768
#define HH 12
#define NN 64
#define GG 2
#define CG 384   // C/G
#define FF 3145728L   // B*C*T
#define S1 1572864L   // B*384*T

// ---------------------------------------------------------------------------
// Generic fp32 tiled GEMM: C(Cout x T) = A(Cout x K) * B(K x T), 64x64 tile,
// 256 threads, 4x4 micro-tile. Template flags:
//   ATRANS: A stored (K x Cout) row-major (ldA = row stride over k)
//   BTRANS: B stored (T x K) row-major (ldB = row stride over t)
//   TOUT:   output stored (T x Cout) row-major (ldC = row stride over t)
//   MODE:   0 none, 1 tanh, 2 mix (out = aux2[m,n]*(aux[m]+acc)),
//           3 ww (decay chain), 4 sigmoid(aux[m]+acc)
// z decomposition: zo = blockIdx.z / zInner, zi = blockIdx.z % zInner
// ---------------------------------------------------------------------------
template<int ATRANS, int BTRANS, int TOUT, int MODE>
__global__ __launch_bounds__(256) void gemm_kernel(
    const float* __restrict__ A, const float* __restrict__ Bm, float* __restrict__ Cm,
    const float* __restrict__ aux, const float* __restrict__ aux2,
    int K, int ldA, int ldB, int ldC, int zInner,
    long sA_o, long sA_i, long sB_o, long sB_i, long sC_o, long sC_i,
    long sAux_i, long sAux2_o)
{
    const int zo = blockIdx.z / zInner;
    const int zi = blockIdx.z % zInner;
    A  += (size_t)zo * sA_o + (size_t)zi * sA_i;
    Bm += (size_t)zo * sB_o + (size_t)zi * sB_i;
    Cm += (size_t)zo * sC_o + (size_t)zi * sC_i;
    if (MODE == 2) { aux += (size_t)zi * sAux_i; aux2 += (size_t)zo * sAux2_o; }

    const int m0t = blockIdx.y * 64;
    const int n0t = blockIdx.x * 64;
    const int tid = threadIdx.x;

    __shared__ float As[16][64];
    __shared__ float Bs[16][64];

    int mi, ni;
    if (TOUT) { mi = (tid & 15) * 4; ni = (tid >> 4) * 4; }
    else      { ni = (tid & 15) * 4; mi = (tid >> 4) * 4; }

    float acc[4][4];
#pragma unroll
    for (int i = 0; i < 4; ++i)
#pragma unroll
        for (int j = 0; j < 4; ++j) acc[i][j] = 0.f;

    for (int k0 = 0; k0 < K; k0 += 16) {
        if (!ATRANS) {
            const int row = tid >> 2;
            const int kc  = (tid & 3) * 4;
            float4 av = *(const float4*)&A[(size_t)(m0t + row) * ldA + k0 + kc];
            As[kc + 0][row] = av.x; As[kc + 1][row] = av.y;
            As[kc + 2][row] = av.z; As[kc + 3][row] = av.w;
        } else {
            const int krow = tid >> 4;
            const int mc   = (tid & 15) * 4;
            *(float4*)&As[krow][mc] = *(const float4*)&A[(size_t)(k0 + krow) * ldA + m0t + mc];
        }
        if (!BTRANS) {
            const int krow = tid >> 4;
            const int tc   = (tid & 15) * 4;
            *(float4*)&Bs[krow][tc] = *(const float4*)&Bm[(size_t)(k0 + krow) * ldB + n0t + tc];
        } else {
            const int trow = tid >> 2;
            const int kc   = (tid & 3) * 4;
            float4 bv = *(const float4*)&Bm[(size_t)(n0t + trow) * ldB + k0 + kc];
            Bs[kc + 0][trow] = bv.x; Bs[kc + 1][trow] = bv.y;
            Bs[kc + 2][trow] = bv.z; Bs[kc + 3][trow] = bv.w;
        }
        __syncthreads();
#pragma unroll
        for (int kk = 0; kk < 16; ++kk) {
            float4 a4 = *(const float4*)&As[kk][mi];
            float4 b4 = *(const float4*)&Bs[kk][ni];
            float am[4] = {a4.x, a4.y, a4.z, a4.w};
            float bn[4] = {b4.x, b4.y, b4.z, b4.w};
#pragma unroll
            for (int i = 0; i < 4; ++i)
#pragma unroll
                for (int j = 0; j < 4; ++j) acc[i][j] = fmaf(am[i], bn[j], acc[i][j]);
        }
        __syncthreads();
    }

    const int mbase = m0t + mi, nbase = n0t + ni;
#pragma unroll
    for (int i = 0; i < 4; ++i) {
        float4 xv;
        if (MODE == 2) xv = *(const float4*)&aux2[(size_t)(mbase + i) * ldC + nbase];
        float xa[4] = {0.f, 0.f, 0.f, 0.f};
        if (MODE == 2) { xa[0] = xv.x; xa[1] = xv.y; xa[2] = xv.z; xa[3] = xv.w; }
#pragma unroll
        for (int j = 0; j < 4; ++j) {
            float v = acc[i][j];
            if (MODE == 1) v = tanhf(v);
            else if (MODE == 2) v = xa[j] * (aux[mbase + i] + v);
            else if (MODE == 3) {
                float u  = aux[mbase + i] + v;
                float sp = fmaxf(-u, 0.f) + log1pf(expf(-fabsf(u)));  // softplus(-u)
                float wl = -sp - 0.5f;
                v = expf(-expf(wl));
            } else if (MODE == 4) {
                float u = aux[mbase + i] + v;
                v = 1.f / (1.f + expf(-u));
            }
            acc[i][j] = v;
        }
    }
    if (!TOUT) {
#pragma unroll
        for (int i = 0; i < 4; ++i) {
            float4 o = {acc[i][0], acc[i][1], acc[i][2], acc[i][3]};
            *(float4*)&Cm[(size_t)(mbase + i) * ldC + nbase] = o;
        }
    } else {
#pragma unroll
        for (int j = 0; j < 4; ++j) {
            float4 o = {acc[0][j], acc[1][j], acc[2][j], acc[3][j]};
            *(float4*)&Cm[(size_t)(nbase + j) * ldC + mbase] = o;
        }
    }
}

// ---------------------------------------------------------------------------
__global__ void pack_aux_kernel(const float* __restrict__ r, const float* __restrict__ w,
                                const float* __restrict__ k, const float* __restrict__ v,
                                const float* __restrict__ a, const float* __restrict__ g,
                                float* __restrict__ paux)
{
    int c = blockIdx.x * blockDim.x + threadIdx.x;
    if (c < CC) {
        paux[0 * CC + c] = 1.f + r[c];
        paux[1 * CC + c] = 1.f + w[c];
        paux[2 * CC + c] = 1.f + k[c];
        paux[3 * CC + c] = 1.f + v[c];
        paux[4 * CC + c] = 1.f + a[c];
        paux[5 * CC + c] = 1.f + g[c];
    }
}

// ---------------------------------------------------------------------------
// E1: per token, kk = k + kvec; per-head L2-normalize; aa=-kkn (over kvec),
// b2=kkn*a (over a). All (B,T,C). One block = one token.
// ---------------------------------------------------------------------------
__global__ __launch_bounds__(256) void e1_kernel(const float* __restrict__ kA,
                                                 float* __restrict__ kvecA,
                                                 float* __restrict__ aA)
{
    const size_t base = (size_t)blockIdx.x * CC;
    const int tid = threadIdx.x;
#pragma unroll
    for (int ch = 0; ch < 3; ++ch) {
        int c = ch * 256 + tid;
        float kk = kA[base + c] + kvecA[base + c];
        float ss = kk * kk;
#pragma unroll
        for (int off = 32; off; off >>= 1) ss += __shfl_xor(ss, off, 64);
        float denom = fmaxf(sqrtf(ss), 1e-12f);
        float kkn = kk / denom;
        float av = aA[base + c];
        kvecA[base + c] = -kkn;       // aa
        aA[base + c]    = kkn * av;   // b2
    }
}

// ---------------------------------------------------------------------------
// WKV-7 recurrence, v8 = EXACT v5 structure (named f0/f1/f2, caller-side
// prefetch, y reduced+stored inline at end of each step — the proven-738µs
// schedule; v6/v7's deferred-y + pointer-folding both regressed) with ONE
// change: all global accesses use 32-bit int offsets from the uniform
// kernel-arg base pointers. This enables the SADDR addressing form
// (global_load_dwordx4 v, v_off, s[base]) — one 32-bit offset register per
// step instead of per-load 64-bit VGPR address arithmetic (~2 VALU x 21
// loads/step saved). Stream footprints are ~12.6MB so int offsets are safe.
// No LDS, no barriers (single wave per block).
// ---------------------------------------------------------------------------
struct WFrag {
    float4 w[4], a[4], b[4], k[4], r[4];
    float vv;
};

__global__ __launch_bounds__(64) void wkv_kernel(
    const float* __restrict__ rA, const float* __restrict__ wA,
    const float* __restrict__ kA, const float* __restrict__ vA,
    const float* __restrict__ aaA, const float* __restrict__ b2A,
    float* __restrict__ yA)
{
    const int blk = blockIdx.x;          // rg*24 + bh  (XCD swizzle)
    const int bh = blk % 24, rg = blk / 24;
    const int b = bh / HH, h = bh - b * HH;
    const int lane = threadIdx.x;
    const int jg = lane >> 4, p = lane & 15;
    const int row = rg * 16 + p;
    const int base = b * TT * CC + h * NN;   // fits easily in int (max ~3.1M)
    const int fo = jg * 16;

    float S[16];
#pragma unroll
    for (int i = 0; i < 16; ++i) S[i] = 0.f;

    WFrag f0, f1, f2;

    auto loadfrag = [&](WFrag& f, int t) {
        const int o = base + t * CC + fo;     // 32-bit offset -> SADDR loads
#pragma unroll
        for (int q = 0; q < 4; ++q) {
            f.w[q] = *(const float4*)&wA[o + 4 * q];
            f.a[q] = *(const float4*)&aaA[o + 4 * q];
            f.b[q] = *(const float4*)&b2A[o + 4 * q];
            f.k[q] = *(const float4*)&kA[o + 4 * q];
            f.r[q] = *(const float4*)&rA[o + 4 * q];
        }
        f.vv = vA[base + t * CC + row];
    };

    auto stepf = [&](const WFrag& f, int t) {
        // off-chain: vk = vv * k  (independent of S and tmp)
        const float vv = f.vv;
        float vk[16];
#pragma unroll
        for (int q = 0; q < 4; ++q) {
            vk[4*q+0] = vv * f.k[q].x;
            vk[4*q+1] = vv * f.k[q].y;
            vk[4*q+2] = vv * f.k[q].z;
            vk[4*q+3] = vv * f.k[q].w;
        }

        // tmp partial over this lane's 16 columns (on chain)
        float t0 = 0.f, t1 = 0.f, t2 = 0.f, t3 = 0.f;
#pragma unroll
        for (int q = 0; q < 4; ++q) {
            float4 a4 = f.a[q];
            t0 = fmaf(S[4*q+0], a4.x, t0);
            t1 = fmaf(S[4*q+1], a4.y, t1);
            t2 = fmaf(S[4*q+2], a4.z, t2);
            t3 = fmaf(S[4*q+3], a4.w, t3);
        }
        float part = (t0 + t1) + (t2 + t3);
        // one DS-latency reduction: 3 independent shfls
        float s16 = __shfl_xor(part, 16, 64);
        float s32 = __shfl_xor(part, 32, 64);
        float s48 = __shfl_xor(part, 48, 64);
        float tmp = (part + s16) + (s32 + s48);

        // state update (2 fma deep from tmp) + y partial (off chain)
        float y0 = 0.f, y1 = 0.f, y2 = 0.f, y3 = 0.f;
#pragma unroll
        for (int q = 0; q < 4; ++q) {
            float4 w4 = f.w[q], b4 = f.b[q], r4 = f.r[q];
            S[4*q+0] = fmaf(S[4*q+0], w4.x, fmaf(tmp, b4.x, vk[4*q+0]));
            y0 = fmaf(S[4*q+0], r4.x, y0);
            S[4*q+1] = fmaf(S[4*q+1], w4.y, fmaf(tmp, b4.y, vk[4*q+1]));
            y1 = fmaf(S[4*q+1], r4.y, y1);
            S[4*q+2] = fmaf(S[4*q+2], w4.z, fmaf(tmp, b4.z, vk[4*q+2]));
            y2 = fmaf(S[4*q+2], r4.z, y2);
            S[4*q+3] = fmaf(S[4*q+3], w4.w, fmaf(tmp, b4.w, vk[4*q+3]));
            y3 = fmaf(S[4*q+3], r4.w, y3);
        }
        // y reduction: feeds only the store — off the recurrence chain
        float yp = (y0 + y1) + (y2 + y3);
        float u16 = __shfl_xor(yp, 16, 64);
        float u32 = __shfl_xor(yp, 32, 64);
        float u48 = __shfl_xor(yp, 48, 64);
        float y = (yp + u16) + (u32 + u48);
        if (jg == 0) yA[base + t * CC + row] = y;
    };

    loadfrag(f0, 0);
    loadfrag(f1, 1);
    loadfrag(f2, 2);

    int t = 0;
    for (; t + 2 < TT; t += 3) {
        stepf(f0, t);
        if (t + 3 < TT) loadfrag(f0, t + 3);
        stepf(f1, t + 1);
        if (t + 4 < TT) loadfrag(f1, t + 4);
        stepf(f2, t + 2);
        if (t + 5 < TT) loadfrag(f2, t + 5);
    }
    // tail (TT = 3*682 + 2): two remaining steps, fragments already loaded
    if (t < TT) stepf(f0, t);
    if (t + 1 < TT) stepf(f1, t + 1);
}

// ---------------------------------------------------------------------------
// E2: per token: RMSNorm(y)*lnw + (sum_head r*k*faaaa)*v, times g, write (B,T,C)
// ---------------------------------------------------------------------------
__global__ __launch_bounds__(256) void e2_kernel(
    const float* __restrict__ yA, const float* __restrict__ rA,
    const float* __restrict__ kA, const float* __restrict__ vA,
    const float* __restrict__ gA, const float* __restrict__ faaaa,
    const float* __restrict__ lnw, float* __restrict__ zA)
{
    const size_t base = (size_t)blockIdx.x * CC;
    const int tid = threadIdx.x;
    const int wave = tid >> 6;
    __shared__ float red[4];
    __shared__ float rk[12];

    float yv[3];
    float ss = 0.f;
#pragma unroll
    for (int ch = 0; ch < 3; ++ch) {
        int c = ch * 256 + tid;
        float y = yA[base + c];
        yv[ch] = y;
        ss = fmaf(y, y, ss);
        float p = rA[base + c] * kA[base + c] * faaaa[c];
#pragma unroll
        for (int off = 32; off; off >>= 1) p += __shfl_xor(p, off, 64);
        if ((tid & 63) == 0) rk[ch * 4 + wave] = p;
    }
#pragma unroll
    for (int off = 32; off; off >>= 1) ss += __shfl_xor(ss, off, 64);
    if ((tid & 63) == 0) red[wave] = ss;
    __syncthreads();
    const float total = red[0] + red[1] + red[2] + red[3];
    const float scale = rsqrtf(total / (float)CC + 1e-5f);
#pragma unroll
    for (int ch = 0; ch < 3; ++ch) {
        int c = ch * 256 + tid;
        float out = yv[ch] * scale * lnw[c] + rk[c >> 6] * vA[base + c];
        zA[base + c] = out * gA[base + c];
    }
}

// ---------------------------------------------------------------------------
extern "C" void kernel_launch(void* const* d_in, const int* in_sizes, int n_in,
                              void* d_out, int out_size, void* d_ws, size_t ws_size,
                              hipStream_t stream)
{
    (void)in_sizes; (void)n_in; (void)out_size; (void)ws_size;
    const float* x        = (const float*)d_in[0];
    const float* tmaa_r   = (const float*)d_in[2];
    const float* tmaa_w   = (const float*)d_in[3];
    const float* tmaa_k   = (const float*)d_in[4];
    const float* tmaa_v   = (const float*)d_in[5];
    const float* tmaa_a   = (const float*)d_in[6];
    const float* tmaa_g   = (const float*)d_in[7];
    const float* tdecay   = (const float*)d_in[8];
    const float* tfaaaa   = (const float*)d_in[9];
    const float* taaaaa   = (const float*)d_in[10];
    const float* maa_w1   = (const float*)d_in[11];
    const float* maa_w2   = (const float*)d_in[12];
    const float* decay_w1 = (const float*)d_in[13];
    const float* decay_w2 = (const float*)d_in[14];
    const float* aaa_w1   = (const float*)d_in[15];
    const float* aaa_w2   = (const float*)d_in[16];
    const float* kkk_w1   = (const float*)d_in[17];
    const float* kkk_w2   = (const float*)d_in[18];
    const float* gate_w1  = (const float*)d_in[19];
    const float* gate_w2  = (const float*)d_in[20];
    const float* w_key    = (const float*)d_in[21];
    const float* w_value  = (const float*)d_in[22];
    const float* w_recept = (const float*)d_in[23];
    const float* w_output = (const float*)d_in[24];
    const float* lnw      = (const float*)d_in[25];
    float* out = (float*)d_out;

    float* ws   = (float*)d_ws;
    float* paux = ws;                 // 6*768
    float* tm   = ws + 8192;          // S1
    float* X6   = tm + S1;            // 6*FF
    float* dh   = X6 + 6 * FF;        // B*64*T = 262144
    float* ah   = dh + 262144;
    float* kh   = ah + 262144;
    float* gh   = kh + 262144;        // B*192*T = 786432
    float* gbuf = gh + 786432;        // FF
    float* ybuf = gbuf + FF;          // FF
    float* zbuf = ybuf + FF;          // FF

    float* xr = X6 + 0 * FF; float* xw = X6 + 1 * FF; float* xk = X6 + 2 * FF;
    float* xv = X6 + 3 * FF; float* xa = X6 + 4 * FF; float* xg = X6 + 5 * FF;
    float* wwB = X6 + 0 * FF; float* rB  = X6 + 1 * FF; float* aaB = X6 + 2 * FF;
    float* b2B = X6 + 3 * FF; float* kB  = X6 + 4 * FF; float* vB  = X6 + 5 * FF;

    const long CT = (long)CC * TT;        // 1572864
    const long TC = (long)TT * CC;        // 1572864

    pack_aux_kernel<<<dim3(3), 256, 0, stream>>>(tmaa_r, tmaa_w, tmaa_k, tmaa_v, tmaa_a, tmaa_g, paux);

    // tm = tanh(maa_w1 @ x)   (B,384,T)
    gemm_kernel<0,0,0,1><<<dim3(32, 6, 2), 256, 0, stream>>>(
        maa_w1, x, tm, nullptr, nullptr,
        768, 768, TT, TT, 1,
        0, 0, CT, 0, 384L * TT, 0, 0, 0);

    // X6[n] = x * (paux[n] + maa_w2[n]^T @ tm_n)   z = b*6 + n
    gemm_kernel<1,0,0,2><<<dim3(32, 12, 12), 256, 0, stream>>>(
        maa_w2, tm, X6, paux, x,
        64, 768, TT, TT, 6,
        0, 64L * 768, 384L * TT, 64L * TT, CT, FF, 768, CT);

    // lora hiddens (tanh)
    gemm_kernel<0,0,0,1><<<dim3(32, 1, 2), 256, 0, stream>>>(
        decay_w1, xw, dh, nullptr, nullptr, 768, 768, TT, TT, 1,
        0, 0, CT, 0, 64L * TT, 0, 0, 0);
    gemm_kernel<0,0,0,1><<<dim3(32, 1, 2), 256, 0, stream>>>(
        aaa_w1, xa, ah, nullptr, nullptr, 768, 768, TT, TT, 1,
        0, 0, CT, 0, 64L * TT, 0, 0, 0);
    gemm_kernel<0,0,0,1><<<dim3(32, 1, 2), 256, 0, stream>>>(
        kkk_w1, xk, kh, nullptr, nullptr, 768, 768, TT, TT, 1,
        0, 0, CT, 0, 64L * TT, 0, 0, 0);
    gemm_kernel<0,0,0,1><<<dim3(32, 3, 2), 256, 0, stream>>>(
        gate_w1, xg, gh, nullptr, nullptr, 768, 768, TT, TT, 1,
        0, 0, CT, 0, 192L * TT, 0, 0, 0);

    // grouped convs -> (B,T,C) transposed outputs. z = b*2 + g
    gemm_kernel<0,0,1,0><<<dim3(32, 6, 4), 256, 0, stream>>>(
        w_recept, xr, rB, nullptr, nullptr, 384, 384, TT, CC, 2,
        0, 384L * 384, CT, 384L * TT, TC, 384, 0, 0);
    gemm_kernel<0,0,1,0><<<dim3(32, 6, 4), 256, 0, stream>>>(
        w_key, xk, kB, nullptr, nullptr, 384, 384, TT, CC, 2,
        0, 384L * 384, CT, 384L * TT, TC, 384, 0, 0);
    gemm_kernel<0,0,1,0><<<dim3(32, 6, 4), 256, 0, stream>>>(
        w_value, xv, vB, nullptr, nullptr, 384, 384, TT, CC, 2,
        0, 384L * 384, CT, 384L * TT, TC, 384, 0, 0);

    // lora outs -> (B,T,C)
    gemm_kernel<0,0,1,3><<<dim3(32, 12, 2), 256, 0, stream>>>(
        decay_w2, dh, wwB, tdecay, nullptr, 64, 64, TT, CC, 1,
        0, 0, 64L * TT, 0, TC, 0, 0, 0);
    gemm_kernel<0,0,1,4><<<dim3(32, 12, 2), 256, 0, stream>>>(
        aaa_w2, ah, b2B /* a for now */, taaaaa, nullptr, 64, 64, TT, CC, 1,
        0, 0, 64L * TT, 0, TC, 0, 0, 0);
    gemm_kernel<0,0,1,0><<<dim3(32, 12, 2), 256, 0, stream>>>(
        kkk_w2, kh, aaB /* kvec for now */, nullptr, nullptr, 64, 64, TT, CC, 1,
        0, 0, 64L * TT, 0, TC, 0, 0, 0);
    gemm_kernel<0,0,1,0><<<dim3(32, 12, 2), 256, 0, stream>>>(
        gate_w2, gh, gbuf, nullptr, nullptr, 192, 192, TT, CC, 1,
        0, 0, 192L * TT, 0, TC, 0, 0, 0);

    // E1: build aa (over kvec slot) and b2 (over a slot)
    e1_kernel<<<dim3(BB * TT), 256, 0, stream>>>(kB, aaB, b2B);

    // WKV recurrence v8: v5 schedule + 32-bit SADDR-form addressing
    wkv_kernel<<<dim3(BB * HH * 4), 64, 0, stream>>>(rB, wwB, kB, vB, aaB, b2B, ybuf);

    // E2: rmsnorm + faaaa bonus + gate
    e2_kernel<<<dim3(BB * TT), 256, 0, stream>>>(ybuf, rB, kB, vB, gbuf, tfaaaa, lnw, zbuf);

    // final grouped conv from (B,T,C) z -> (B,C,T) out.  z = b*2 + g
    gemm_kernel<0,1,0,0><<<dim3(32, 6, 4), 256, 0, stream>>>(
        w_output, zbuf, out, nullptr, nullptr, 384, 384, CC, TT, 2,
        0, 384L * 384, TC, 384, CT, 384L * TT, 0, 0);
}

// Round 9
// 1152.901 us; speedup vs baseline: 8.0732x; 1.0975x over previous
//
#include <hip/hip_runtime.h>
#include <math.h>

// Problem constants
#define BB 2
#define TT 2048
#define CC 768
#define HH 12
#define NN 64
#define GG 2
#define CG 384   // C/G
#define FF 3145728L   // B*C*T
#define S1 1572864L   // B*384*T

// ---------------------------------------------------------------------------
// Generic fp32 tiled GEMM: C(Cout x T) = A(Cout x K) * B(K x T), 64x64 tile,
// 256 threads, 4x4 micro-tile. Template flags:
//   ATRANS: A stored (K x Cout) row-major (ldA = row stride over k)
//   BTRANS: B stored (T x K) row-major (ldB = row stride over t)
//   TOUT:   output stored (T x Cout) row-major (ldC = row stride over t)
//   MODE:   0 none, 1 tanh, 2 mix (out = aux2[m,n]*(aux[m]+acc)),
//           3 ww (decay chain), 4 sigmoid(aux[m]+acc)
// z decomposition: zo = blockIdx.z / zInner, zi = blockIdx.z % zInner
// ---------------------------------------------------------------------------
template<int ATRANS, int BTRANS, int TOUT, int MODE>
__global__ __launch_bounds__(256) void gemm_kernel(
    const float* __restrict__ A, const float* __restrict__ Bm, float* __restrict__ Cm,
    const float* __restrict__ aux, const float* __restrict__ aux2,
    int K, int ldA, int ldB, int ldC, int zInner,
    long sA_o, long sA_i, long sB_o, long sB_i, long sC_o, long sC_i,
    long sAux_i, long sAux2_o)
{
    const int zo = blockIdx.z / zInner;
    const int zi = blockIdx.z % zInner;
    A  += (size_t)zo * sA_o + (size_t)zi * sA_i;
    Bm += (size_t)zo * sB_o + (size_t)zi * sB_i;
    Cm += (size_t)zo * sC_o + (size_t)zi * sC_i;
    if (MODE == 2) { aux += (size_t)zi * sAux_i; aux2 += (size_t)zo * sAux2_o; }

    const int m0t = blockIdx.y * 64;
    const int n0t = blockIdx.x * 64;
    const int tid = threadIdx.x;

    __shared__ float As[16][64];
    __shared__ float Bs[16][64];

    int mi, ni;
    if (TOUT) { mi = (tid & 15) * 4; ni = (tid >> 4) * 4; }
    else      { ni = (tid & 15) * 4; mi = (tid >> 4) * 4; }

    float acc[4][4];
#pragma unroll
    for (int i = 0; i < 4; ++i)
#pragma unroll
        for (int j = 0; j < 4; ++j) acc[i][j] = 0.f;

    for (int k0 = 0; k0 < K; k0 += 16) {
        if (!ATRANS) {
            const int row = tid >> 2;
            const int kc  = (tid & 3) * 4;
            float4 av = *(const float4*)&A[(size_t)(m0t + row) * ldA + k0 + kc];
            As[kc + 0][row] = av.x; As[kc + 1][row] = av.y;
            As[kc + 2][row] = av.z; As[kc + 3][row] = av.w;
        } else {
            const int krow = tid >> 4;
            const int mc   = (tid & 15) * 4;
            *(float4*)&As[krow][mc] = *(const float4*)&A[(size_t)(k0 + krow) * ldA + m0t + mc];
        }
        if (!BTRANS) {
            const int krow = tid >> 4;
            const int tc   = (tid & 15) * 4;
            *(float4*)&Bs[krow][tc] = *(const float4*)&Bm[(size_t)(k0 + krow) * ldB + n0t + tc];
        } else {
            const int trow = tid >> 2;
            const int kc   = (tid & 3) * 4;
            float4 bv = *(const float4*)&Bm[(size_t)(n0t + trow) * ldB + k0 + kc];
            Bs[kc + 0][trow] = bv.x; Bs[kc + 1][trow] = bv.y;
            Bs[kc + 2][trow] = bv.z; Bs[kc + 3][trow] = bv.w;
        }
        __syncthreads();
#pragma unroll
        for (int kk = 0; kk < 16; ++kk) {
            float4 a4 = *(const float4*)&As[kk][mi];
            float4 b4 = *(const float4*)&Bs[kk][ni];
            float am[4] = {a4.x, a4.y, a4.z, a4.w};
            float bn[4] = {b4.x, b4.y, b4.z, b4.w};
#pragma unroll
            for (int i = 0; i < 4; ++i)
#pragma unroll
                for (int j = 0; j < 4; ++j) acc[i][j] = fmaf(am[i], bn[j], acc[i][j]);
        }
        __syncthreads();
    }

    const int mbase = m0t + mi, nbase = n0t + ni;
#pragma unroll
    for (int i = 0; i < 4; ++i) {
        float4 xv;
        if (MODE == 2) xv = *(const float4*)&aux2[(size_t)(mbase + i) * ldC + nbase];
        float xa[4] = {0.f, 0.f, 0.f, 0.f};
        if (MODE == 2) { xa[0] = xv.x; xa[1] = xv.y; xa[2] = xv.z; xa[3] = xv.w; }
#pragma unroll
        for (int j = 0; j < 4; ++j) {
            float v = acc[i][j];
            if (MODE == 1) v = tanhf(v);
            else if (MODE == 2) v = xa[j] * (aux[mbase + i] + v);
            else if (MODE == 3) {
                float u  = aux[mbase + i] + v;
                float sp = fmaxf(-u, 0.f) + log1pf(expf(-fabsf(u)));  // softplus(-u)
                float wl = -sp - 0.5f;
                v = expf(-expf(wl));
            } else if (MODE == 4) {
                float u = aux[mbase + i] + v;
                v = 1.f / (1.f + expf(-u));
            }
            acc[i][j] = v;
        }
    }
    if (!TOUT) {
#pragma unroll
        for (int i = 0; i < 4; ++i) {
            float4 o = {acc[i][0], acc[i][1], acc[i][2], acc[i][3]};
            *(float4*)&Cm[(size_t)(mbase + i) * ldC + nbase] = o;
        }
    } else {
#pragma unroll
        for (int j = 0; j < 4; ++j) {
            float4 o = {acc[0][j], acc[1][j], acc[2][j], acc[3][j]};
            *(float4*)&Cm[(size_t)(nbase + j) * ldC + mbase] = o;
        }
    }
}

// ---------------------------------------------------------------------------
__global__ void pack_aux_kernel(const float* __restrict__ r, const float* __restrict__ w,
                                const float* __restrict__ k, const float* __restrict__ v,
                                const float* __restrict__ a, const float* __restrict__ g,
                                float* __restrict__ paux)
{
    int c = blockIdx.x * blockDim.x + threadIdx.x;
    if (c < CC) {
        paux[0 * CC + c] = 1.f + r[c];
        paux[1 * CC + c] = 1.f + w[c];
        paux[2 * CC + c] = 1.f + k[c];
        paux[3 * CC + c] = 1.f + v[c];
        paux[4 * CC + c] = 1.f + a[c];
        paux[5 * CC + c] = 1.f + g[c];
    }
}

// ---------------------------------------------------------------------------
// E1: per token, kk = k + kvec; per-head L2-normalize; aa=-kkn (over kvec),
// b2=kkn*a (over a). All (B,T,C). One block = one token.
// ---------------------------------------------------------------------------
__global__ __launch_bounds__(256) void e1_kernel(const float* __restrict__ kA,
                                                 float* __restrict__ kvecA,
                                                 float* __restrict__ aA)
{
    const size_t base = (size_t)blockIdx.x * CC;
    const int tid = threadIdx.x;
#pragma unroll
    for (int ch = 0; ch < 3; ++ch) {
        int c = ch * 256 + tid;
        float kk = kA[base + c] + kvecA[base + c];
        float ss = kk * kk;
#pragma unroll
        for (int off = 32; off; off >>= 1) ss += __shfl_xor(ss, off, 64);
        float denom = fmaxf(sqrtf(ss), 1e-12f);
        float kkn = kk / denom;
        float av = aA[base + c];
        kvecA[base + c] = -kkn;       // aa
        aA[base + c]    = kkn * av;   // b2
    }
}

// ---------------------------------------------------------------------------
// WKV-7 recurrence, v9 = v8 (v5 schedule + 32-bit SADDR addressing, 664µs)
// with the column split widened 4 -> 8 ways: lane = jg*8+p (jg=0..7 column
// group, p=0..7), row = rg*8+p, 8 blocks per (b,h) (192 total). Each lane
// holds S[row][8jg..8jg+7] (8 VGPRs) — per-step per-lane work halves
// (~61 VALU + 11 loads vs ~95 + 21). Cross-group reduction is still ONE
// DS-latency round: 7 independent shfl_xor (masks 8..56), every lane ends
// with the full sum. XCD-sibling locality preserved: blk = rg*24 + bh,
// 24 % 8 == 0 so all 8 rg-siblings of a (b,h) share one XCD's L2.
// No LDS, no barriers (single wave per block).
// ---------------------------------------------------------------------------
struct WFrag {
    float4 w[2], a[2], b[2], k[2], r[2];
    float vv;
};

__global__ __launch_bounds__(64) void wkv_kernel(
    const float* __restrict__ rA, const float* __restrict__ wA,
    const float* __restrict__ kA, const float* __restrict__ vA,
    const float* __restrict__ aaA, const float* __restrict__ b2A,
    float* __restrict__ yA)
{
    const int blk = blockIdx.x;          // rg*24 + bh  (XCD swizzle)
    const int bh = blk % 24, rg = blk / 24;
    const int b = bh / HH, h = bh - b * HH;
    const int lane = threadIdx.x;
    const int jg = lane >> 3, p = lane & 7;
    const int row = rg * 8 + p;
    const int base = b * TT * CC + h * NN;   // fits easily in int
    const int fo = jg * 8;

    float S[8];
#pragma unroll
    for (int i = 0; i < 8; ++i) S[i] = 0.f;

    WFrag f0, f1, f2;

    auto loadfrag = [&](WFrag& f, int t) {
        const int o = base + t * CC + fo;     // 32-bit offset -> SADDR loads
#pragma unroll
        for (int q = 0; q < 2; ++q) {
            f.w[q] = *(const float4*)&wA[o + 4 * q];
            f.a[q] = *(const float4*)&aaA[o + 4 * q];
            f.b[q] = *(const float4*)&b2A[o + 4 * q];
            f.k[q] = *(const float4*)&kA[o + 4 * q];
            f.r[q] = *(const float4*)&rA[o + 4 * q];
        }
        f.vv = vA[base + t * CC + row];
    };

    auto stepf = [&](const WFrag& f, int t) {
        // off-chain: vk = vv * k
        const float vv = f.vv;
        float vk[8];
#pragma unroll
        for (int q = 0; q < 2; ++q) {
            vk[4*q+0] = vv * f.k[q].x;
            vk[4*q+1] = vv * f.k[q].y;
            vk[4*q+2] = vv * f.k[q].z;
            vk[4*q+3] = vv * f.k[q].w;
        }

        // tmp partial over this lane's 8 columns (on chain)
        float t0 = 0.f, t1 = 0.f, t2 = 0.f, t3 = 0.f;
#pragma unroll
        for (int q = 0; q < 2; ++q) {
            float4 a4 = f.a[q];
            t0 = fmaf(S[4*q+0], a4.x, t0);
            t1 = fmaf(S[4*q+1], a4.y, t1);
            t2 = fmaf(S[4*q+2], a4.z, t2);
            t3 = fmaf(S[4*q+3], a4.w, t3);
        }
        float part = (t0 + t1) + (t2 + t3);
        // one DS-latency reduction across the 8 column groups: 7 indep shfls
        float s08 = __shfl_xor(part,  8, 64);
        float s16 = __shfl_xor(part, 16, 64);
        float s24 = __shfl_xor(part, 24, 64);
        float s32 = __shfl_xor(part, 32, 64);
        float s40 = __shfl_xor(part, 40, 64);
        float s48 = __shfl_xor(part, 48, 64);
        float s56 = __shfl_xor(part, 56, 64);
        float tmp = ((part + s08) + (s16 + s24)) + ((s32 + s40) + (s48 + s56));

        // state update (2 fma deep from tmp) + y partial (off chain)
        float y0 = 0.f, y1 = 0.f, y2 = 0.f, y3 = 0.f;
#pragma unroll
        for (int q = 0; q < 2; ++q) {
            float4 w4 = f.w[q], b4 = f.b[q], r4 = f.r[q];
            S[4*q+0] = fmaf(S[4*q+0], w4.x, fmaf(tmp, b4.x, vk[4*q+0]));
            y0 = fmaf(S[4*q+0], r4.x, y0);
            S[4*q+1] = fmaf(S[4*q+1], w4.y, fmaf(tmp, b4.y, vk[4*q+1]));
            y1 = fmaf(S[4*q+1], r4.y, y1);
            S[4*q+2] = fmaf(S[4*q+2], w4.z, fmaf(tmp, b4.z, vk[4*q+2]));
            y2 = fmaf(S[4*q+2], r4.z, y2);
            S[4*q+3] = fmaf(S[4*q+3], w4.w, fmaf(tmp, b4.w, vk[4*q+3]));
            y3 = fmaf(S[4*q+3], r4.w, y3);
        }
        // y reduction: feeds only the store — off the recurrence chain
        float yp = (y0 + y1) + (y2 + y3);
        float u08 = __shfl_xor(yp,  8, 64);
        float u16 = __shfl_xor(yp, 16, 64);
        float u24 = __shfl_xor(yp, 24, 64);
        float u32 = __shfl_xor(yp, 32, 64);
        float u40 = __shfl_xor(yp, 40, 64);
        float u48 = __shfl_xor(yp, 48, 64);
        float u56 = __shfl_xor(yp, 56, 64);
        float y = ((yp + u08) + (u16 + u24)) + ((u32 + u40) + (u48 + u56));
        if (jg == 0) yA[base + t * CC + row] = y;
    };

    loadfrag(f0, 0);
    loadfrag(f1, 1);
    loadfrag(f2, 2);

    int t = 0;
    for (; t + 2 < TT; t += 3) {
        stepf(f0, t);
        if (t + 3 < TT) loadfrag(f0, t + 3);
        stepf(f1, t + 1);
        if (t + 4 < TT) loadfrag(f1, t + 4);
        stepf(f2, t + 2);
        if (t + 5 < TT) loadfrag(f2, t + 5);
    }
    // tail (TT = 3*682 + 2): two remaining steps, fragments already loaded
    if (t < TT) stepf(f0, t);
    if (t + 1 < TT) stepf(f1, t + 1);
}

// ---------------------------------------------------------------------------
// E2: per token: RMSNorm(y)*lnw + (sum_head r*k*faaaa)*v, times g, write (B,T,C)
// ---------------------------------------------------------------------------
__global__ __launch_bounds__(256) void e2_kernel(
    const float* __restrict__ yA, const float* __restrict__ rA,
    const float* __restrict__ kA, const float* __restrict__ vA,
    const float* __restrict__ gA, const float* __restrict__ faaaa,
    const float* __restrict__ lnw, float* __restrict__ zA)
{
    const size_t base = (size_t)blockIdx.x * CC;
    const int tid = threadIdx.x;
    const int wave = tid >> 6;
    __shared__ float red[4];
    __shared__ float rk[12];

    float yv[3];
    float ss = 0.f;
#pragma unroll
    for (int ch = 0; ch < 3; ++ch) {
        int c = ch * 256 + tid;
        float y = yA[base + c];
        yv[ch] = y;
        ss = fmaf(y, y, ss);
        float p = rA[base + c] * kA[base + c] * faaaa[c];
#pragma unroll
        for (int off = 32; off; off >>= 1) p += __shfl_xor(p, off, 64);
        if ((tid & 63) == 0) rk[ch * 4 + wave] = p;
    }
#pragma unroll
    for (int off = 32; off; off >>= 1) ss += __shfl_xor(ss, off, 64);
    if ((tid & 63) == 0) red[wave] = ss;
    __syncthreads();
    const float total = red[0] + red[1] + red[2] + red[3];
    const float scale = rsqrtf(total / (float)CC + 1e-5f);
#pragma unroll
    for (int ch = 0; ch < 3; ++ch) {
        int c = ch * 256 + tid;
        float out = yv[ch] * scale * lnw[c] + rk[c >> 6] * vA[base + c];
        zA[base + c] = out * gA[base + c];
    }
}

// ---------------------------------------------------------------------------
extern "C" void kernel_launch(void* const* d_in, const int* in_sizes, int n_in,
                              void* d_out, int out_size, void* d_ws, size_t ws_size,
                              hipStream_t stream)
{
    (void)in_sizes; (void)n_in; (void)out_size; (void)ws_size;
    const float* x        = (const float*)d_in[0];
    const float* tmaa_r   = (const float*)d_in[2];
    const float* tmaa_w   = (const float*)d_in[3];
    const float* tmaa_k   = (const float*)d_in[4];
    const float* tmaa_v   = (const float*)d_in[5];
    const float* tmaa_a   = (const float*)d_in[6];
    const float* tmaa_g   = (const float*)d_in[7];
    const float* tdecay   = (const float*)d_in[8];
    const float* tfaaaa   = (const float*)d_in[9];
    const float* taaaaa   = (const float*)d_in[10];
    const float* maa_w1   = (const float*)d_in[11];
    const float* maa_w2   = (const float*)d_in[12];
    const float* decay_w1 = (const float*)d_in[13];
    const float* decay_w2 = (const float*)d_in[14];
    const float* aaa_w1   = (const float*)d_in[15];
    const float* aaa_w2   = (const float*)d_in[16];
    const float* kkk_w1   = (const float*)d_in[17];
    const float* kkk_w2   = (const float*)d_in[18];
    const float* gate_w1  = (const float*)d_in[19];
    const float* gate_w2  = (const float*)d_in[20];
    const float* w_key    = (const float*)d_in[21];
    const float* w_value  = (const float*)d_in[22];
    const float* w_recept = (const float*)d_in[23];
    const float* w_output = (const float*)d_in[24];
    const float* lnw      = (const float*)d_in[25];
    float* out = (float*)d_out;

    float* ws   = (float*)d_ws;
    float* paux = ws;                 // 6*768
    float* tm   = ws + 8192;          // S1
    float* X6   = tm + S1;            // 6*FF
    float* dh   = X6 + 6 * FF;        // B*64*T = 262144
    float* ah   = dh + 262144;
    float* kh   = ah + 262144;
    float* gh   = kh + 262144;        // B*192*T = 786432
    float* gbuf = gh + 786432;        // FF
    float* ybuf = gbuf + FF;          // FF
    float* zbuf = ybuf + FF;          // FF

    float* xr = X6 + 0 * FF; float* xw = X6 + 1 * FF; float* xk = X6 + 2 * FF;
    float* xv = X6 + 3 * FF; float* xa = X6 + 4 * FF; float* xg = X6 + 5 * FF;
    float* wwB = X6 + 0 * FF; float* rB  = X6 + 1 * FF; float* aaB = X6 + 2 * FF;
    float* b2B = X6 + 3 * FF; float* kB  = X6 + 4 * FF; float* vB  = X6 + 5 * FF;

    const long CT = (long)CC * TT;        // 1572864
    const long TC = (long)TT * CC;        // 1572864

    pack_aux_kernel<<<dim3(3), 256, 0, stream>>>(tmaa_r, tmaa_w, tmaa_k, tmaa_v, tmaa_a, tmaa_g, paux);

    // tm = tanh(maa_w1 @ x)   (B,384,T)
    gemm_kernel<0,0,0,1><<<dim3(32, 6, 2), 256, 0, stream>>>(
        maa_w1, x, tm, nullptr, nullptr,
        768, 768, TT, TT, 1,
        0, 0, CT, 0, 384L * TT, 0, 0, 0);

    // X6[n] = x * (paux[n] + maa_w2[n]^T @ tm_n)   z = b*6 + n
    gemm_kernel<1,0,0,2><<<dim3(32, 12, 12), 256, 0, stream>>>(
        maa_w2, tm, X6, paux, x,
        64, 768, TT, TT, 6,
        0, 64L * 768, 384L * TT, 64L * TT, CT, FF, 768, CT);

    // lora hiddens (tanh)
    gemm_kernel<0,0,0,1><<<dim3(32, 1, 2), 256, 0, stream>>>(
        decay_w1, xw, dh, nullptr, nullptr, 768, 768, TT, TT, 1,
        0, 0, CT, 0, 64L * TT, 0, 0, 0);
    gemm_kernel<0,0,0,1><<<dim3(32, 1, 2), 256, 0, stream>>>(
        aaa_w1, xa, ah, nullptr, nullptr, 768, 768, TT, TT, 1,
        0, 0, CT, 0, 64L * TT, 0, 0, 0);
    gemm_kernel<0,0,0,1><<<dim3(32, 1, 2), 256, 0, stream>>>(
        kkk_w1, xk, kh, nullptr, nullptr, 768, 768, TT, TT, 1,
        0, 0, CT, 0, 64L * TT, 0, 0, 0);
    gemm_kernel<0,0,0,1><<<dim3(32, 3, 2), 256, 0, stream>>>(
        gate_w1, xg, gh, nullptr, nullptr, 768, 768, TT, TT, 1,
        0, 0, CT, 0, 192L * TT, 0, 0, 0);

    // grouped convs -> (B,T,C) transposed outputs. z = b*2 + g
    gemm_kernel<0,0,1,0><<<dim3(32, 6, 4), 256, 0, stream>>>(
        w_recept, xr, rB, nullptr, nullptr, 384, 384, TT, CC, 2,
        0, 384L * 384, CT, 384L * TT, TC, 384, 0, 0);
    gemm_kernel<0,0,1,0><<<dim3(32, 6, 4), 256, 0, stream>>>(
        w_key, xk, kB, nullptr, nullptr, 384, 384, TT, CC, 2,
        0, 384L * 384, CT, 384L * TT, TC, 384, 0, 0);
    gemm_kernel<0,0,1,0><<<dim3(32, 6, 4), 256, 0, stream>>>(
        w_value, xv, vB, nullptr, nullptr, 384, 384, TT, CC, 2,
        0, 384L * 384, CT, 384L * TT, TC, 384, 0, 0);

    // lora outs -> (B,T,C)
    gemm_kernel<0,0,1,3><<<dim3(32, 12, 2), 256, 0, stream>>>(
        decay_w2, dh, wwB, tdecay, nullptr, 64, 64, TT, CC, 1,
        0, 0, 64L * TT, 0, TC, 0, 0, 0);
    gemm_kernel<0,0,1,4><<<dim3(32, 12, 2), 256, 0, stream>>>(
        aaa_w2, ah, b2B /* a for now */, taaaaa, nullptr, 64, 64, TT, CC, 1,
        0, 0, 64L * TT, 0, TC, 0, 0, 0);
    gemm_kernel<0,0,1,0><<<dim3(32, 12, 2), 256, 0, stream>>>(
        kkk_w2, kh, aaB /* kvec for now */, nullptr, nullptr, 64, 64, TT, CC, 1,
        0, 0, 64L * TT, 0, TC, 0, 0, 0);
    gemm_kernel<0,0,1,0><<<dim3(32, 12, 2), 256, 0, stream>>>(
        gate_w2, gh, gbuf, nullptr, nullptr, 192, 192, TT, CC, 1,
        0, 0, 192L * TT, 0, TC, 0, 0, 0);

    // E1: build aa (over kvec slot) and b2 (over a slot)
    e1_kernel<<<dim3(BB * TT), 256, 0, stream>>>(kB, aaB, b2B);

    // WKV recurrence v9: 8-way column split, 192 waves
    wkv_kernel<<<dim3(BB * HH * 8), 64, 0, stream>>>(rB, wwB, kB, vB, aaB, b2B, ybuf);

    // E2: rmsnorm + faaaa bonus + gate
    e2_kernel<<<dim3(BB * TT), 256, 0, stream>>>(ybuf, rB, kB, vB, gbuf, tfaaaa, lnw, zbuf);

    // final grouped conv from (B,T,C) z -> (B,C,T) out.  z = b*2 + g
    gemm_kernel<0,1,0,0><<<dim3(32, 6, 4), 256, 0, stream>>>(
        w_output, zbuf, out, nullptr, nullptr, 384, 384, CC, TT, 2,
        0, 384L * 384, TC, 384, CT, 384L * TT, 0, 0);
}